// Round 1
// baseline (1108.702 us; speedup 1.0000x reference)
//
#include <hip/hip_runtime.h>
#include <hip/hip_bf16.h>

// Segmented GroupNorm: N rows x C=128 channels, G=32 groups, Cg=4.
// Pass 1: per-(seg,group) sum/sumsq via LDS bins + global atomics.
// Finalize: mean/inv per (seg,group) -> float2 table.
// Pass 2: elementwise normalize.

#define C_CHANNELS 128
#define GROUPS 32
#define SEG_CAP 256        // global bin capacity (ws)
#define LDS_SEG_CAP 128    // per-block LDS bin capacity
#define EPS 1e-5f

__global__ __launch_bounds__(256) void gn_pass1(
    const float4* __restrict__ x, const int* __restrict__ seg,
    float* __restrict__ gsum, float* __restrict__ gsq, float* __restrict__ gcnt,
    const int* __restrict__ nInstPtr, int N)
{
    __shared__ float lsum[LDS_SEG_CAP * GROUPS];
    __shared__ float lsq [LDS_SEG_CAP * GROUPS];
    __shared__ float lcnt[LDS_SEG_CAP];

    for (int i = threadIdx.x; i < LDS_SEG_CAP * GROUPS; i += blockDim.x) {
        lsum[i] = 0.f; lsq[i] = 0.f;
    }
    for (int i = threadIdx.x; i < LDS_SEG_CAP; i += blockDim.x) lcnt[i] = 0.f;
    __syncthreads();

    const int g = threadIdx.x & 31;               // group id, loop-invariant
    const long long total  = (long long)N * GROUPS;
    const long long stride = (long long)gridDim.x * blockDim.x;   // multiple of 32
    long long i = (long long)blockIdx.x * blockDim.x + threadIdx.x;

    // x2 unrolled: two independent 16B loads in flight per wave iteration
    for (; i + stride < total; i += 2 * stride) {
        long long i2 = i + stride;
        int row1 = (int)(i  >> 5);
        int row2 = (int)(i2 >> 5);
        float4 v1 = x[i];
        float4 v2 = x[i2];
        int s1 = seg[row1];
        int s2 = seg[row2];
        float sum1 = (v1.x + v1.y) + (v1.z + v1.w);
        float sq1  = v1.x*v1.x + v1.y*v1.y + v1.z*v1.z + v1.w*v1.w;
        float sum2 = (v2.x + v2.y) + (v2.z + v2.w);
        float sq2  = v2.x*v2.x + v2.y*v2.y + v2.z*v2.z + v2.w*v2.w;
        if (s1 < LDS_SEG_CAP) {
            atomicAdd(&lsum[s1*GROUPS + g], sum1);
            atomicAdd(&lsq [s1*GROUPS + g], sq1);
            if (g == 0) atomicAdd(&lcnt[s1], 1.0f);
        } else {
            atomicAdd(&gsum[s1*GROUPS + g], sum1);
            atomicAdd(&gsq [s1*GROUPS + g], sq1);
            if (g == 0) atomicAdd(&gcnt[s1], 1.0f);
        }
        if (s2 < LDS_SEG_CAP) {
            atomicAdd(&lsum[s2*GROUPS + g], sum2);
            atomicAdd(&lsq [s2*GROUPS + g], sq2);
            if (g == 0) atomicAdd(&lcnt[s2], 1.0f);
        } else {
            atomicAdd(&gsum[s2*GROUPS + g], sum2);
            atomicAdd(&gsq [s2*GROUPS + g], sq2);
            if (g == 0) atomicAdd(&gcnt[s2], 1.0f);
        }
    }
    // tail
    for (; i < total; i += stride) {
        int row = (int)(i >> 5);
        float4 v = x[i];
        int s = seg[row];
        float sum = (v.x + v.y) + (v.z + v.w);
        float sq  = v.x*v.x + v.y*v.y + v.z*v.z + v.w*v.w;
        if (s < LDS_SEG_CAP) {
            atomicAdd(&lsum[s*GROUPS + g], sum);
            atomicAdd(&lsq [s*GROUPS + g], sq);
            if (g == 0) atomicAdd(&lcnt[s], 1.0f);
        } else {
            atomicAdd(&gsum[s*GROUPS + g], sum);
            atomicAdd(&gsq [s*GROUPS + g], sq);
            if (g == 0) atomicAdd(&gcnt[s], 1.0f);
        }
    }
    __syncthreads();

    // flush LDS bins -> global, rotated start per block to spread L2 contention
    int S = *nInstPtr;
    int lim = min(S, LDS_SEG_CAP);
    int nb = lim * GROUPS;
    int rot = (int)((blockIdx.x * 64u) % (unsigned)nb);
    for (int t = threadIdx.x; t < nb; t += blockDim.x) {
        int j = t + rot; if (j >= nb) j -= nb;
        float a = lsum[j], b = lsq[j];
        if (a != 0.f || b != 0.f) {
            atomicAdd(&gsum[j], a);
            atomicAdd(&gsq [j], b);
        }
    }
    for (int t = threadIdx.x; t < lim; t += blockDim.x) {
        float c = lcnt[t];
        if (c != 0.f) atomicAdd(&gcnt[t], c);
    }
}

__global__ __launch_bounds__(256) void gn_finalize(
    const float* __restrict__ gsum, const float* __restrict__ gsq,
    const float* __restrict__ gcnt, float2* __restrict__ stats,
    const int* __restrict__ nInstPtr)
{
    int S = *nInstPtr;
    int i = blockIdx.x * blockDim.x + threadIdx.x;
    if (i < S * GROUPS) {
        int s = i >> 5;
        float cnt = gcnt[s];
        float denom = fmaxf(cnt * 4.0f, 1.0f);
        float mean = gsum[i] / denom;
        float var  = gsq[i] / denom - mean * mean;
        float inv  = rsqrtf(var + EPS);
        stats[i] = make_float2(mean, inv);
    }
}

__global__ __launch_bounds__(256) void gn_pass2(
    const float4* __restrict__ x, const int* __restrict__ seg,
    const float2* __restrict__ stats,
    const float4* __restrict__ gamma4, const float4* __restrict__ beta4,
    float4* __restrict__ out, int N)
{
    const int g = threadIdx.x & 31;               // loop-invariant group id
    const float4 gm = gamma4[g];
    const float4 bt = beta4[g];
    const long long total  = (long long)N * GROUPS;
    const long long stride = (long long)gridDim.x * blockDim.x;
    for (long long i = (long long)blockIdx.x * blockDim.x + threadIdx.x;
         i < total; i += stride) {
        int row = (int)(i >> 5);
        float4 v = x[i];
        int s = seg[row];
        float2 mi = stats[s * GROUPS + g];
        float4 o;
        o.x = (v.x - mi.x) * mi.y * gm.x + bt.x;
        o.y = (v.y - mi.x) * mi.y * gm.y + bt.y;
        o.z = (v.z - mi.x) * mi.y * gm.z + bt.z;
        o.w = (v.w - mi.x) * mi.y * gm.w + bt.w;
        out[i] = o;
    }
}

extern "C" void kernel_launch(void* const* d_in, const int* in_sizes, int n_in,
                              void* d_out, int out_size, void* d_ws, size_t ws_size,
                              hipStream_t stream) {
    const float* feat  = (const float*)d_in[0];
    const int*   seg   = (const int*)d_in[1];
    const float* gamma = (const float*)d_in[2];
    const float* beta  = (const float*)d_in[3];
    const int*   nInst = (const int*)d_in[4];
    const int N = in_sizes[0] / C_CHANNELS;

    // ws layout: gsum [SEG_CAP*32]f | gsq [SEG_CAP*32]f | gcnt [SEG_CAP]f | stats [SEG_CAP*32]float2
    float* gsum = (float*)d_ws;                                   // 32768 B
    float* gsq  = gsum + SEG_CAP * GROUPS;                        // 32768 B
    float* gcnt = gsq  + SEG_CAP * GROUPS;                        // 1024 B
    float2* stats = (float2*)(gcnt + SEG_CAP);                    // 66560 B offset (8-aligned)
    size_t zero_bytes = (size_t)(2 * SEG_CAP * GROUPS + SEG_CAP) * sizeof(float);

    hipMemsetAsync(d_ws, 0, zero_bytes, stream);

    gn_pass1<<<512, 256, 0, stream>>>(
        (const float4*)feat, seg, gsum, gsq, gcnt, nInst, N);

    gn_finalize<<<(SEG_CAP * GROUPS + 255) / 256, 256, 0, stream>>>(
        gsum, gsq, gcnt, stats, nInst);

    gn_pass2<<<2048, 256, 0, stream>>>(
        (const float4*)feat, seg, stats,
        (const float4*)gamma, (const float4*)beta,
        (float4*)d_out, N);
}